// Round 5
// baseline (336.415 us; speedup 1.0000x reference)
//
#include <hip/hip_runtime.h>

typedef __attribute__((ext_vector_type(8))) short short8;
typedef __attribute__((ext_vector_type(4))) float v4f;

__device__ __forceinline__ ushort f2bf(float x) {
    unsigned u = __float_as_uint(x);
    u = u + 0x7fffu + ((u >> 16) & 1u);     // round-to-nearest-even
    return (ushort)(u >> 16);
}
__device__ __forceinline__ float bflo(unsigned u) { return __uint_as_float(u << 16); }
__device__ __forceinline__ float bfhi(unsigned u) { return __uint_as_float(u & 0xffff0000u); }

// K0: pack [W_src; W_skip] -> bf16 Wb[256][128], plus dst histogram (merged launch)
__global__ __launch_bounds__(256) void k0_misc(
    const float* __restrict__ Wsrc, const float* __restrict__ Wskip,
    ushort* __restrict__ Wb, const int* __restrict__ dst,
    int* __restrict__ counts, int E_)
{
    int b = blockIdx.x;
    if (b < 128) {
        int i = b * 256 + threadIdx.x;     // 0..32767
        float v = (i < 16384) ? Wsrc[i] : Wskip[i - 16384];
        Wb[i] = f2bf(v);
    } else {
        int e = (b - 128) * 256 + threadIdx.x;
        if (e < E_) atomicAdd(&counts[dst[e]], 1);
    }
}

// MEGA: blocks [0, nbg) run the bf16 MFMA projection GEMM (+ fused el/er);
// blocks [nbg, nbg+nbs) run scanA (per-1024 exclusive scan of counts).
// The two paths are independent (GEMM needs Wb/feat; scanA needs counts).
__global__ __launch_bounds__(256) void k_mega(
    const float* __restrict__ feat, const ushort* __restrict__ Wb,
    const float* __restrict__ bsrc, const float* __restrict__ bskip,
    const float* __restrict__ attn_l, const float* __restrict__ attn_r,
    ushort* __restrict__ feat_src, ushort* __restrict__ skip_bf,
    float* __restrict__ el, float* __restrict__ er, int n,
    const int* __restrict__ counts, int* __restrict__ row_start,
    int* __restrict__ blocksum, int nbg)
{
    __shared__ ushort A_lds[64][136];          // pad +8 -> conflict-balanced b128
    __shared__ int sdata[256];
    const int tid = threadIdx.x;

    if (blockIdx.x >= nbg) {
        // ---- scanA path ----
        int base = (blockIdx.x - nbg) * 1024 + tid * 4;
        int v[4]; int s = 0;
        #pragma unroll
        for (int k = 0; k < 4; ++k) {
            int idx = base + k;
            v[k] = (idx < n) ? counts[idx] : 0;
            s += v[k];
        }
        sdata[tid] = s;
        __syncthreads();
        for (int off = 1; off < 256; off <<= 1) {
            int t = (tid >= off) ? sdata[tid - off] : 0;
            __syncthreads();
            sdata[tid] += t;
            __syncthreads();
        }
        if (tid == 255) blocksum[blockIdx.x - nbg] = sdata[255];
        int run = (tid > 0) ? sdata[tid - 1] : 0;
        #pragma unroll
        for (int k = 0; k < 4; ++k) {
            int idx = base + k;
            if (idx < n) row_start[idx] = run;
            run += v[k];
        }
        return;
    }

    // ---- GEMM path ----
    const int wave = tid >> 6, lane = tid & 63;
    const int quad = lane >> 4, l16 = lane & 15;
    const int row0 = blockIdx.x * 64;

    {
        int r = tid >> 2;
        int c0 = (tid & 3) * 32;
        int grow = row0 + r;
        float4 f[8];
        if (grow < n) {
            const float4* p = (const float4*)(feat + (size_t)grow * 128 + c0);
            #pragma unroll
            for (int i = 0; i < 8; ++i) f[i] = p[i];
        } else {
            #pragma unroll
            for (int i = 0; i < 8; ++i) f[i] = make_float4(0.f, 0.f, 0.f, 0.f);
        }
        #pragma unroll
        for (int i = 0; i < 4; ++i) {
            short8 v;
            v[0] = (short)f2bf(f[2*i].x);   v[1] = (short)f2bf(f[2*i].y);
            v[2] = (short)f2bf(f[2*i].z);   v[3] = (short)f2bf(f[2*i].w);
            v[4] = (short)f2bf(f[2*i+1].x); v[5] = (short)f2bf(f[2*i+1].y);
            v[6] = (short)f2bf(f[2*i+1].z); v[7] = (short)f2bf(f[2*i+1].w);
            *(short8*)&A_lds[r][c0 + i * 8] = v;
        }
    }
    __syncthreads();

    v4f acc[4][4] = {};
    const int n0 = wave * 64;

    #pragma unroll
    for (int k0 = 0; k0 < 128; k0 += 32) {
        short8 a[4], b[4];
        #pragma unroll
        for (int mt = 0; mt < 4; ++mt)
            a[mt] = *(const short8*)&A_lds[mt * 16 + l16][k0 + quad * 8];
        #pragma unroll
        for (int nt = 0; nt < 4; ++nt) {
            int c = n0 + nt * 16 + l16;
            b[nt] = *(const short8*)(Wb + (size_t)c * 128 + k0 + quad * 8);
        }
        #pragma unroll
        for (int mt = 0; mt < 4; ++mt)
            #pragma unroll
            for (int nt = 0; nt < 4; ++nt)
                acc[mt][nt] = __builtin_amdgcn_mfma_f32_16x16x32_bf16(
                    a[mt], b[nt], acc[mt][nt], 0, 0, 0);
    }

    #pragma unroll
    for (int nt = 0; nt < 4; ++nt) {
        int c = n0 + nt * 16 + l16;
        float bias = (c < 128) ? bsrc[c] : bskip[c - 128];
        #pragma unroll
        for (int mt = 0; mt < 4; ++mt)
            #pragma unroll
            for (int i = 0; i < 4; ++i)
                acc[mt][nt][i] += bias;
    }

    #pragma unroll
    for (int nt = 0; nt < 4; ++nt) {
        int c = n0 + nt * 16 + l16;
        #pragma unroll
        for (int mt = 0; mt < 4; ++mt) {
            #pragma unroll
            for (int i = 0; i < 4; ++i) {
                int row = row0 + mt * 16 + quad * 4 + i;
                if (row < n) {
                    ushort v = f2bf(acc[mt][nt][i]);
                    if (c < 128) feat_src[(size_t)row * 128 + c] = v;
                    else         skip_bf[(size_t)row * 128 + (c - 128)] = v;
                }
            }
        }
    }

    if (wave < 2) {
        const int hb = n0 >> 5;
        float al0 = attn_l[n0 + l16],      al1 = attn_l[n0 + 16 + l16];
        float al2 = attn_l[n0 + 32 + l16], al3 = attn_l[n0 + 48 + l16];
        float ar0 = attn_r[n0 + l16],      ar1 = attn_r[n0 + 16 + l16];
        float ar2 = attn_r[n0 + 32 + l16], ar3 = attn_r[n0 + 48 + l16];
        #pragma unroll
        for (int mt = 0; mt < 4; ++mt) {
            #pragma unroll
            for (int i = 0; i < 4; ++i) {
                float pl0 = acc[mt][0][i] * al0 + acc[mt][1][i] * al1;
                float pl1 = acc[mt][2][i] * al2 + acc[mt][3][i] * al3;
                float pr0 = acc[mt][0][i] * ar0 + acc[mt][1][i] * ar1;
                float pr1 = acc[mt][2][i] * ar2 + acc[mt][3][i] * ar3;
                #pragma unroll
                for (int m = 1; m < 16; m <<= 1) {
                    pl0 += __shfl_xor(pl0, m); pl1 += __shfl_xor(pl1, m);
                    pr0 += __shfl_xor(pr0, m); pr1 += __shfl_xor(pr1, m);
                }
                int row = row0 + mt * 16 + quad * 4 + i;
                if (l16 == 0 && row < n) {
                    *(float2*)(el + (size_t)row * 4 + hb) = make_float2(pl0, pl1);
                    *(float2*)(er + (size_t)row * 4 + hb) = make_float2(pr0, pr1);
                }
            }
        }
    }
}

// scanBC: each block re-scans the <=128 block sums in LDS (replaces scanB),
// then applies offsets, mirrors into cursor, caps row_start[n]=E.
__global__ __launch_bounds__(256) void k_scanBC(
    int* __restrict__ row_start, const int* __restrict__ blocksum,
    int* __restrict__ cursor, int n, int E_, int nb)
{
    __shared__ int sc[128];
    int tid = threadIdx.x;
    if (tid < 128) sc[tid] = (tid < nb) ? blocksum[tid] : 0;
    __syncthreads();
    for (int off = 1; off < 128; off <<= 1) {
        int t = 0;
        if (tid < 128 && tid >= off) t = sc[tid - off];
        __syncthreads();
        if (tid < 128) sc[tid] += t;
        __syncthreads();
    }
    int i = blockIdx.x * 256 + tid;
    if (i < n) {
        int bb = i >> 10;
        int v = row_start[i] + ((bb > 0) ? sc[bb - 1] : 0);
        row_start[i] = v;
        cursor[i] = v;
    }
    if (i == n) row_start[n] = E_;
}

// fill: bucket edges by dst AND precompute per-edge softmax weights for all 4
// heads (fp32), so k3 never touches el/er or exp.
__global__ __launch_bounds__(256) void k_fill(
    const int* __restrict__ src, const int* __restrict__ dst,
    int* __restrict__ cursor,
    const float4* __restrict__ el4, const float4* __restrict__ er4,
    int* __restrict__ csr_src, float4* __restrict__ csr_w4, int E_)
{
    int e = blockIdx.x * 256 + threadIdx.x;
    if (e >= E_) return;
    int s = src[e], d = dst[e];
    int pos = atomicAdd(&cursor[d], 1);
    float4 a = el4[s], b = er4[d];
    float4 w; float t;
    t = a.x + b.x; w.x = __expf(t >= 0.f ? t : 0.2f * t);
    t = a.y + b.y; w.y = __expf(t >= 0.f ? t : 0.2f * t);
    t = a.z + b.z; w.z = __expf(t >= 0.f ? t : 0.2f * t);
    t = a.w + b.w; w.w = __expf(t >= 0.f ? t : 0.2f * t);
    csr_src[pos] = s;
    csr_w4[pos] = w;
}

// K3: fused aggregate + gate + LayerNorm + PReLU. One wave per dst node.
// Per edge: one sequential L1-hot w load + one random 256B feat-row gather.
// 8-wide unrolled with independent accumulators for MLP.
__global__ __launch_bounds__(256) void k3_fused(
    const int* __restrict__ row_start, const int* __restrict__ csr_src,
    const float* __restrict__ csr_w,
    const ushort* __restrict__ feat_src, const ushort* __restrict__ skip_bf,
    const float* __restrict__ Wg, const float* __restrict__ bg,
    const float* __restrict__ lng, const float* __restrict__ lnb,
    const float* __restrict__ pa, float* __restrict__ out, int n)
{
    int node = blockIdx.x * 4 + (threadIdx.x >> 6);
    if (node >= n) return;
    int lane = threadIdx.x & 63;
    int j = lane * 2;
    int h = lane >> 4;                     // head

    int beg = row_start[node], end = row_start[node + 1];
    const ushort* fbase = feat_src + j;

    float ac0[8] = {}, ac1[8] = {}, ws[8] = {};

    for (int p0 = beg; p0 < end; p0 += 64) {
        int pv = p0 + lane;
        int sv = csr_src[pv < end ? pv : end - 1];   // one coalesced load / 64 edges
        int cnt = end - p0; if (cnt > 64) cnt = 64;
        int i = 0;
        for (; i + 7 < cnt; i += 8) {
            int s[8]; float w[8]; unsigned u[8];
            #pragma unroll
            for (int k = 0; k < 8; ++k) s[k] = __shfl(sv, i + k);
            #pragma unroll
            for (int k = 0; k < 8; ++k) {
                w[k] = csr_w[(size_t)(p0 + i + k) * 4 + h];
                u[k] = *(const unsigned*)(fbase + (size_t)s[k] * 128);
            }
            #pragma unroll
            for (int k = 0; k < 8; ++k) {
                ws[k] += w[k];
                ac0[k] = fmaf(w[k], bflo(u[k]), ac0[k]);
                ac1[k] = fmaf(w[k], bfhi(u[k]), ac1[k]);
            }
        }
        for (; i < cnt; ++i) {
            int s = __shfl(sv, i);
            float w = csr_w[(size_t)(p0 + i) * 4 + h];
            unsigned u = *(const unsigned*)(fbase + (size_t)s * 128);
            ws[0] += w;
            ac0[0] = fmaf(w, bflo(u), ac0[0]);
            ac1[0] = fmaf(w, bfhi(u), ac1[0]);
        }
    }
    float wsum = ((ws[0]+ws[1])+(ws[2]+ws[3])) + ((ws[4]+ws[5])+(ws[6]+ws[7]));
    float acc0 = ((ac0[0]+ac0[1])+(ac0[2]+ac0[3])) + ((ac0[4]+ac0[5])+(ac0[6]+ac0[7]));
    float acc1 = ((ac1[0]+ac1[1])+(ac1[2]+ac1[3])) + ((ac1[4]+ac1[5])+(ac1[6]+ac1[7]));
    float inv = (wsum > 0.f) ? 1.f / wsum : 0.f;   // deg-0 node -> rst = 0
    float r0 = acc0 * inv, r1 = acc1 * inv;

    unsigned su = *(const unsigned*)(skip_bf + (size_t)node * 128 + j);
    float sx = bflo(su), sy = bfhi(su);

    float g = r0 * Wg[j]     + sx * Wg[128 + j]     + (r0 - sx) * Wg[256 + j]
            + r1 * Wg[j + 1] + sy * Wg[128 + j + 1] + (r1 - sy) * Wg[256 + j + 1];
    #pragma unroll
    for (int m = 1; m < 64; m <<= 1) g += __shfl_xor(g, m);
    float gate = 1.f / (1.f + __expf(-(g + bg[0])));

    float x0 = gate * r0 + (1.f - gate) * sx;
    float x1 = gate * r1 + (1.f - gate) * sy;

    float sm = x0 + x1, sq = x0 * x0 + x1 * x1;
    #pragma unroll
    for (int m = 1; m < 64; m <<= 1) {
        sm += __shfl_xor(sm, m);
        sq += __shfl_xor(sq, m);
    }
    float mu = sm * (1.f / 128.f);
    float var = sq * (1.f / 128.f) - mu * mu;
    float rs = rsqrtf(var + 1e-5f);
    float alpha = pa[0];
    float y0 = (x0 - mu) * rs * lng[j]     + lnb[j];
    float y1 = (x1 - mu) * rs * lng[j + 1] + lnb[j + 1];
    y0 = y0 >= 0.f ? y0 : alpha * y0;
    y1 = y1 >= 0.f ? y1 : alpha * y1;
    *(float2*)(out + (size_t)node * 128 + j) = make_float2(y0, y1);
}

extern "C" void kernel_launch(void* const* d_in, const int* in_sizes, int n_in,
                              void* d_out, int out_size, void* d_ws, size_t ws_size,
                              hipStream_t stream)
{
    const float* feat   = (const float*)d_in[0];
    const int*   src    = (const int*)d_in[1];
    const int*   dst    = (const int*)d_in[2];
    const float* Wsrc   = (const float*)d_in[3];
    const float* bsrc   = (const float*)d_in[4];
    const float* attn_l = (const float*)d_in[5];
    const float* attn_r = (const float*)d_in[6];
    const float* Wskip  = (const float*)d_in[7];
    const float* bskip  = (const float*)d_in[8];
    const float* Wg     = (const float*)d_in[9];
    const float* bg     = (const float*)d_in[10];
    const float* lng    = (const float*)d_in[11];
    const float* lnb    = (const float*)d_in[12];
    const float* pa     = (const float*)d_in[13];

    const int n = in_sizes[0] / 128;
    const int E = in_sizes[1];
    float* out = (float*)d_out;

    // workspace: el f32[4n] | er f32[4n] | feat_src bf16[128n] | skip bf16[128n]
    //  | Wb bf16[32768] | counts[n] | row_start[n+1] | cursor[n] | blocksum[128]
    //  | csr_src[E] | csr_w f32[4E]
    float*  el       = (float*)d_ws;
    float*  er       = el + (size_t)n * 4;
    ushort* feat_src = (ushort*)(er + (size_t)n * 4);
    ushort* skip_bf  = feat_src + (size_t)n * 128;
    ushort* Wb       = skip_bf + (size_t)n * 128;
    int*    counts    = (int*)(Wb + 32768);
    int*    row_start = counts + n;
    int*    cursor    = row_start + (n + 1);
    int*    blocksum  = cursor + n;
    int*    csr_src   = blocksum + 128;
    float*  csr_w     = (float*)(csr_src + E);

    hipMemsetAsync(counts, 0, (size_t)n * sizeof(int), stream);

    k0_misc<<<128 + (E + 255) / 256, 256, 0, stream>>>(Wsrc, Wskip, Wb, dst, counts, E);

    int nbg = (n + 63) / 64;
    int nbs = (n + 1023) / 1024;
    k_mega<<<nbg + nbs, 256, 0, stream>>>(
        feat, Wb, bsrc, bskip, attn_l, attn_r, feat_src, skip_bf, el, er, n,
        counts, row_start, blocksum, nbg);

    k_scanBC<<<(n + 256) / 256, 256, 0, stream>>>(row_start, blocksum, cursor, n, E, nbs);
    k_fill<<<(E + 255) / 256, 256, 0, stream>>>(
        src, dst, cursor, (const float4*)el, (const float4*)er,
        csr_src, (float4*)csr_w, E);

    k3_fused<<<(n + 3) / 4, 256, 0, stream>>>(
        row_start, csr_src, csr_w, feat_src, skip_bf, Wg, bg, lng, lnb, pa, out, n);
}

// Round 6
// 290.521 us; speedup vs baseline: 1.1580x; 1.1580x over previous
//
#include <hip/hip_runtime.h>

typedef __attribute__((ext_vector_type(8))) short short8;
typedef __attribute__((ext_vector_type(4))) float v4f;

__device__ __forceinline__ ushort f2bf(float x) {
    unsigned u = __float_as_uint(x);
    u = u + 0x7fffu + ((u >> 16) & 1u);     // round-to-nearest-even
    return (ushort)(u >> 16);
}
__device__ __forceinline__ float bflo(unsigned u) { return __uint_as_float(u << 16); }
__device__ __forceinline__ float bfhi(unsigned u) { return __uint_as_float(u & 0xffff0000u); }

// K0: pack [W_src; W_skip] -> bf16 Wb[256][128], plus dst histogram (merged launch)
__global__ __launch_bounds__(256) void k0_misc(
    const float* __restrict__ Wsrc, const float* __restrict__ Wskip,
    ushort* __restrict__ Wb, const int* __restrict__ dst,
    int* __restrict__ counts, int E_)
{
    int b = blockIdx.x;
    if (b < 128) {
        int i = b * 256 + threadIdx.x;     // 0..32767
        float v = (i < 16384) ? Wsrc[i] : Wskip[i - 16384];
        Wb[i] = f2bf(v);
    } else {
        int e = (b - 128) * 256 + threadIdx.x;
        if (e < E_) atomicAdd(&counts[dst[e]], 1);
    }
}

// MEGA: blocks [0, nbg) run the bf16 MFMA projection GEMM (+ fused el/er);
// blocks [nbg, nbg+nbs) run scanA. Independent paths.
// MFMA operands SWAPPED (mfma(b,a,acc)) so acc[mt][nt][i] =
// C[row = mt*16 + l16][col = n0 + nt*16 + quad*4 + i] — register index i runs
// along columns => 8B packed stores, float4 bias, 2-shfl el/er reductions.
__global__ __launch_bounds__(256) void k_mega(
    const float* __restrict__ feat, const ushort* __restrict__ Wb,
    const float* __restrict__ bsrc, const float* __restrict__ bskip,
    const float* __restrict__ attn_l, const float* __restrict__ attn_r,
    ushort* __restrict__ feat_src, ushort* __restrict__ skip_bf,
    float* __restrict__ el, float* __restrict__ er, int n,
    const int* __restrict__ counts, int* __restrict__ row_start,
    int* __restrict__ blocksum, int nbg)
{
    __shared__ ushort A_lds[64][136];          // pad +8 -> conflict-balanced b128
    __shared__ int sdata[256];
    const int tid = threadIdx.x;

    if (blockIdx.x >= nbg) {
        // ---- scanA path ----
        int base = (blockIdx.x - nbg) * 1024 + tid * 4;
        int v[4]; int s = 0;
        #pragma unroll
        for (int k = 0; k < 4; ++k) {
            int idx = base + k;
            v[k] = (idx < n) ? counts[idx] : 0;
            s += v[k];
        }
        sdata[tid] = s;
        __syncthreads();
        for (int off = 1; off < 256; off <<= 1) {
            int t = (tid >= off) ? sdata[tid - off] : 0;
            __syncthreads();
            sdata[tid] += t;
            __syncthreads();
        }
        if (tid == 255) blocksum[blockIdx.x - nbg] = sdata[255];
        int run = (tid > 0) ? sdata[tid - 1] : 0;
        #pragma unroll
        for (int k = 0; k < 4; ++k) {
            int idx = base + k;
            if (idx < n) row_start[idx] = run;
            run += v[k];
        }
        return;
    }

    // ---- GEMM path ----
    const int wave = tid >> 6, lane = tid & 63;
    const int quad = lane >> 4, l16 = lane & 15;
    const int row0 = blockIdx.x * 64;

    {
        int r = tid >> 2;
        int c0 = (tid & 3) * 32;
        int grow = row0 + r;
        float4 f[8];
        if (grow < n) {
            const float4* p = (const float4*)(feat + (size_t)grow * 128 + c0);
            #pragma unroll
            for (int i = 0; i < 8; ++i) f[i] = p[i];
        } else {
            #pragma unroll
            for (int i = 0; i < 8; ++i) f[i] = make_float4(0.f, 0.f, 0.f, 0.f);
        }
        #pragma unroll
        for (int i = 0; i < 4; ++i) {
            short8 v;
            v[0] = (short)f2bf(f[2*i].x);   v[1] = (short)f2bf(f[2*i].y);
            v[2] = (short)f2bf(f[2*i].z);   v[3] = (short)f2bf(f[2*i].w);
            v[4] = (short)f2bf(f[2*i+1].x); v[5] = (short)f2bf(f[2*i+1].y);
            v[6] = (short)f2bf(f[2*i+1].z); v[7] = (short)f2bf(f[2*i+1].w);
            *(short8*)&A_lds[r][c0 + i * 8] = v;
        }
    }
    __syncthreads();

    v4f acc[4][4] = {};
    const int n0 = wave * 64;

    #pragma unroll
    for (int k0 = 0; k0 < 128; k0 += 32) {
        short8 a[4], b[4];
        #pragma unroll
        for (int mt = 0; mt < 4; ++mt)
            a[mt] = *(const short8*)&A_lds[mt * 16 + l16][k0 + quad * 8];
        #pragma unroll
        for (int nt = 0; nt < 4; ++nt) {
            int c = n0 + nt * 16 + l16;
            b[nt] = *(const short8*)(Wb + (size_t)c * 128 + k0 + quad * 8);
        }
        #pragma unroll
        for (int mt = 0; mt < 4; ++mt)
            #pragma unroll
            for (int nt = 0; nt < 4; ++nt)
                acc[mt][nt] = __builtin_amdgcn_mfma_f32_16x16x32_bf16(
                    b[nt], a[mt], acc[mt][nt], 0, 0, 0);   // SWAPPED -> transposed tile
    }

    // bias: cols cb..cb+3 contiguous per lane -> float4
    #pragma unroll
    for (int nt = 0; nt < 4; ++nt) {
        int cb = n0 + nt * 16 + quad * 4;
        const float* bp = (n0 < 128) ? (bsrc + cb) : (bskip + (cb - 128));
        float4 bias = *(const float4*)bp;
        #pragma unroll
        for (int mt = 0; mt < 4; ++mt) {
            acc[mt][nt][0] += bias.x;
            acc[mt][nt][1] += bias.y;
            acc[mt][nt][2] += bias.z;
            acc[mt][nt][3] += bias.w;
        }
    }

    // store: pack 4 consecutive cols -> one 8B store per (mt,nt)
    #pragma unroll
    for (int mt = 0; mt < 4; ++mt) {
        int row = row0 + mt * 16 + l16;
        if (row < n) {
            #pragma unroll
            for (int nt = 0; nt < 4; ++nt) {
                int cb = n0 + nt * 16 + quad * 4;
                unsigned lo = (unsigned)f2bf(acc[mt][nt][0]) |
                              ((unsigned)f2bf(acc[mt][nt][1]) << 16);
                unsigned hi = (unsigned)f2bf(acc[mt][nt][2]) |
                              ((unsigned)f2bf(acc[mt][nt][3]) << 16);
                uint2 pv = make_uint2(lo, hi);
                if (n0 < 128) *(uint2*)(feat_src + (size_t)row * 128 + cb) = pv;
                else          *(uint2*)(skip_bf  + (size_t)row * 128 + (cb - 128)) = pv;
            }
        }
    }

    // el/er: waves 0,1 (cols < 128). Row r = mt*16+l16 is spread over the 4
    // quads (cols) -> in-register nt/i sums + shfl_xor(16), shfl_xor(32).
    if (wave < 2) {
        const int hb = n0 >> 5;
        float4 al[4], ar[4];
        #pragma unroll
        for (int nt = 0; nt < 4; ++nt) {
            int cb = n0 + nt * 16 + quad * 4;
            al[nt] = *(const float4*)(attn_l + cb);
            ar[nt] = *(const float4*)(attn_r + cb);
        }
        #pragma unroll
        for (int mt = 0; mt < 4; ++mt) {
            float pl0 = 0.f, pl1 = 0.f, pr0 = 0.f, pr1 = 0.f;
            #pragma unroll
            for (int i = 0; i < 4; ++i) {
                float a0 = acc[mt][0][i], a1 = acc[mt][1][i];
                float a2 = acc[mt][2][i], a3 = acc[mt][3][i];
                const float* pal0 = (const float*)&al[0]; const float* pal1 = (const float*)&al[1];
                const float* pal2 = (const float*)&al[2]; const float* pal3 = (const float*)&al[3];
                const float* par0 = (const float*)&ar[0]; const float* par1 = (const float*)&ar[1];
                const float* par2 = (const float*)&ar[2]; const float* par3 = (const float*)&ar[3];
                pl0 = fmaf(a0, pal0[i], fmaf(a1, pal1[i], pl0));
                pl1 = fmaf(a2, pal2[i], fmaf(a3, pal3[i], pl1));
                pr0 = fmaf(a0, par0[i], fmaf(a1, par1[i], pr0));
                pr1 = fmaf(a2, par2[i], fmaf(a3, par3[i], pr1));
            }
            pl0 += __shfl_xor(pl0, 16); pl0 += __shfl_xor(pl0, 32);
            pl1 += __shfl_xor(pl1, 16); pl1 += __shfl_xor(pl1, 32);
            pr0 += __shfl_xor(pr0, 16); pr0 += __shfl_xor(pr0, 32);
            pr1 += __shfl_xor(pr1, 16); pr1 += __shfl_xor(pr1, 32);
            int row = row0 + mt * 16 + l16;
            if (lane < 16 && row < n) {
                *(float2*)(el + (size_t)row * 4 + hb) = make_float2(pl0, pl1);
                *(float2*)(er + (size_t)row * 4 + hb) = make_float2(pr0, pr1);
            }
        }
    }
}

// scanBC: each block re-scans the <=128 block sums in LDS, applies offsets,
// mirrors into cursor, caps row_start[n]=E.
__global__ __launch_bounds__(256) void k_scanBC(
    int* __restrict__ row_start, const int* __restrict__ blocksum,
    int* __restrict__ cursor, int n, int E_, int nb)
{
    __shared__ int sc[128];
    int tid = threadIdx.x;
    if (tid < 128) sc[tid] = (tid < nb) ? blocksum[tid] : 0;
    __syncthreads();
    for (int off = 1; off < 128; off <<= 1) {
        int t = 0;
        if (tid < 128 && tid >= off) t = sc[tid - off];
        __syncthreads();
        if (tid < 128) sc[tid] += t;
        __syncthreads();
    }
    int i = blockIdx.x * 256 + tid;
    if (i < n) {
        int bb = i >> 10;
        int v = row_start[i] + ((bb > 0) ? sc[bb - 1] : 0);
        row_start[i] = v;
        cursor[i] = v;
    }
    if (i == n) row_start[n] = E_;
}

// fill: bucket src ids by dst (order within bucket irrelevant)
__global__ __launch_bounds__(256) void k_fill(const int* __restrict__ src,
                                              const int* __restrict__ dst,
                                              int* __restrict__ cursor,
                                              int* __restrict__ csr_src, int E_)
{
    int e = blockIdx.x * 256 + threadIdx.x;
    if (e >= E_) return;
    int pos = atomicAdd(&cursor[dst[e]], 1);
    csr_src[pos] = src[e];
}

// K3 (R4 version verbatim): fused softmax-aggregate + gate + LayerNorm + PReLU.
// One wave per dst node; 4-wide unroll (28 VGPR -> ~70% occupancy, which is
// what this latency-bound kernel needs — 8-wide/44 VGPR regressed it).
__global__ __launch_bounds__(256) void k3_fused(
    const int* __restrict__ row_start, const int* __restrict__ csr_src,
    const float* __restrict__ el, const float* __restrict__ er,
    const ushort* __restrict__ feat_src, const ushort* __restrict__ skip_bf,
    const float* __restrict__ Wg, const float* __restrict__ bg,
    const float* __restrict__ lng, const float* __restrict__ lnb,
    const float* __restrict__ pa, float* __restrict__ out, int n)
{
    int node = blockIdx.x * 4 + (threadIdx.x >> 6);
    if (node >= n) return;
    int lane = threadIdx.x & 63;
    int j = lane * 2;
    int h = j >> 5;

    int beg = row_start[node], end = row_start[node + 1];
    float er_h = er[(size_t)node * 4 + h];
    const ushort* fbase = feat_src + j;

    float a0 = 0.f, a1 = 0.f, b0 = 0.f, b1 = 0.f;
    float c0 = 0.f, c1 = 0.f, d0 = 0.f, d1 = 0.f;
    float ws0 = 0.f, ws1 = 0.f, ws2 = 0.f, ws3 = 0.f;

    for (int p0 = beg; p0 < end; p0 += 64) {
        int pv = p0 + lane;
        int sv = csr_src[pv < end ? pv : end - 1];   // one coalesced load / 64 edges
        int cnt = end - p0; if (cnt > 64) cnt = 64;
        int i = 0;
        for (; i + 3 < cnt; i += 4) {
            int s0 = __shfl(sv, i),     s1 = __shfl(sv, i + 1);
            int s2 = __shfl(sv, i + 2), s3 = __shfl(sv, i + 3);
            float e0 = el[(size_t)s0 * 4 + h];
            float e1 = el[(size_t)s1 * 4 + h];
            float e2 = el[(size_t)s2 * 4 + h];
            float e3 = el[(size_t)s3 * 4 + h];
            unsigned u0 = *(const unsigned*)(fbase + (size_t)s0 * 128);
            unsigned u1 = *(const unsigned*)(fbase + (size_t)s1 * 128);
            unsigned u2 = *(const unsigned*)(fbase + (size_t)s2 * 128);
            unsigned u3 = *(const unsigned*)(fbase + (size_t)s3 * 128);
            float t0 = e0 + er_h, t1 = e1 + er_h, t2 = e2 + er_h, t3 = e3 + er_h;
            float w0 = __expf(t0 >= 0.f ? t0 : 0.2f * t0);
            float w1 = __expf(t1 >= 0.f ? t1 : 0.2f * t1);
            float w2 = __expf(t2 >= 0.f ? t2 : 0.2f * t2);
            float w3 = __expf(t3 >= 0.f ? t3 : 0.2f * t3);
            ws0 += w0; ws1 += w1; ws2 += w2; ws3 += w3;
            a0 = fmaf(w0, bflo(u0), a0); a1 = fmaf(w0, bfhi(u0), a1);
            b0 = fmaf(w1, bflo(u1), b0); b1 = fmaf(w1, bfhi(u1), b1);
            c0 = fmaf(w2, bflo(u2), c0); c1 = fmaf(w2, bfhi(u2), c1);
            d0 = fmaf(w3, bflo(u3), d0); d1 = fmaf(w3, bfhi(u3), d1);
        }
        for (; i < cnt; ++i) {
            int s = __shfl(sv, i);
            float t = el[(size_t)s * 4 + h] + er_h;
            float w = __expf(t >= 0.f ? t : 0.2f * t);
            unsigned u = *(const unsigned*)(fbase + (size_t)s * 128);
            ws0 += w;
            a0 = fmaf(w, bflo(u), a0); a1 = fmaf(w, bfhi(u), a1);
        }
    }
    float wsum = (ws0 + ws1) + (ws2 + ws3);
    float acc0 = (a0 + b0) + (c0 + d0);
    float acc1 = (a1 + b1) + (c1 + d1);
    float inv = (wsum > 0.f) ? 1.f / wsum : 0.f;   // deg-0 node -> rst = 0
    float r0 = acc0 * inv, r1 = acc1 * inv;

    unsigned su = *(const unsigned*)(skip_bf + (size_t)node * 128 + j);
    float sx = bflo(su), sy = bfhi(su);

    float g = r0 * Wg[j]     + sx * Wg[128 + j]     + (r0 - sx) * Wg[256 + j]
            + r1 * Wg[j + 1] + sy * Wg[128 + j + 1] + (r1 - sy) * Wg[256 + j + 1];
    #pragma unroll
    for (int m = 1; m < 64; m <<= 1) g += __shfl_xor(g, m);
    float gate = 1.f / (1.f + __expf(-(g + bg[0])));

    float x0 = gate * r0 + (1.f - gate) * sx;
    float x1 = gate * r1 + (1.f - gate) * sy;

    float sm = x0 + x1, sq = x0 * x0 + x1 * x1;
    #pragma unroll
    for (int m = 1; m < 64; m <<= 1) {
        sm += __shfl_xor(sm, m);
        sq += __shfl_xor(sq, m);
    }
    float mu = sm * (1.f / 128.f);
    float var = sq * (1.f / 128.f) - mu * mu;
    float rs = rsqrtf(var + 1e-5f);
    float alpha = pa[0];
    float y0 = (x0 - mu) * rs * lng[j]     + lnb[j];
    float y1 = (x1 - mu) * rs * lng[j + 1] + lnb[j + 1];
    y0 = y0 >= 0.f ? y0 : alpha * y0;
    y1 = y1 >= 0.f ? y1 : alpha * y1;
    *(float2*)(out + (size_t)node * 128 + j) = make_float2(y0, y1);
}

extern "C" void kernel_launch(void* const* d_in, const int* in_sizes, int n_in,
                              void* d_out, int out_size, void* d_ws, size_t ws_size,
                              hipStream_t stream)
{
    const float* feat   = (const float*)d_in[0];
    const int*   src    = (const int*)d_in[1];
    const int*   dst    = (const int*)d_in[2];
    const float* Wsrc   = (const float*)d_in[3];
    const float* bsrc   = (const float*)d_in[4];
    const float* attn_l = (const float*)d_in[5];
    const float* attn_r = (const float*)d_in[6];
    const float* Wskip  = (const float*)d_in[7];
    const float* bskip  = (const float*)d_in[8];
    const float* Wg     = (const float*)d_in[9];
    const float* bg     = (const float*)d_in[10];
    const float* lng    = (const float*)d_in[11];
    const float* lnb    = (const float*)d_in[12];
    const float* pa     = (const float*)d_in[13];

    const int n = in_sizes[0] / 128;
    const int E = in_sizes[1];
    float* out = (float*)d_out;

    // workspace: el f32[4n] | er f32[4n] | feat_src bf16[128n] | skip bf16[128n]
    //  | Wb bf16[32768] | counts[n] | row_start[n+1] | cursor[n] | blocksum[128]
    //  | csr_src[E]
    float*  el       = (float*)d_ws;
    float*  er       = el + (size_t)n * 4;
    ushort* feat_src = (ushort*)(er + (size_t)n * 4);
    ushort* skip_bf  = feat_src + (size_t)n * 128;
    ushort* Wb       = skip_bf + (size_t)n * 128;
    int*    counts    = (int*)(Wb + 32768);
    int*    row_start = counts + n;
    int*    cursor    = row_start + (n + 1);
    int*    blocksum  = cursor + n;
    int*    csr_src   = blocksum + 128;

    hipMemsetAsync(counts, 0, (size_t)n * sizeof(int), stream);

    k0_misc<<<128 + (E + 255) / 256, 256, 0, stream>>>(Wsrc, Wskip, Wb, dst, counts, E);

    int nbg = (n + 63) / 64;
    int nbs = (n + 1023) / 1024;
    k_mega<<<nbg + nbs, 256, 0, stream>>>(
        feat, Wb, bsrc, bskip, attn_l, attn_r, feat_src, skip_bf, el, er, n,
        counts, row_start, blocksum, nbg);

    k_scanBC<<<(n + 256) / 256, 256, 0, stream>>>(row_start, blocksum, cursor, n, E, nbs);
    k_fill<<<(E + 255) / 256, 256, 0, stream>>>(src, dst, cursor, csr_src, E);

    k3_fused<<<(n + 3) / 4, 256, 0, stream>>>(
        row_start, csr_src, el, er, feat_src, skip_bf, Wg, bg, lng, lnb, pa, out, n);
}